// Round 10
// baseline (75.077 us; speedup 1.0000x reference)
//
#include <hip/hip_runtime.h>

#define N_WORD 32000
#define DIM    300
#define KP     320           // K padded to 10 x 32 for MFMA
#define LROW   328           // LDS row stride in bf16 (656 B: odd*16 -> 2-way max)
#define BQ     32
#define WW     8
#define NNEG   2392
#define PERB   (WW*NNEG)     // 19136
#define NTOT   (BQ*PERB)     // 612352
#define VB     64            // word rows per GEMM block
#define NGEMB  (N_WORD/VB)   // 500
#define NBLK3  1024

typedef __attribute__((ext_vector_type(8))) short short8;   // 8 bf16 = 4 VGPR
typedef __attribute__((ext_vector_type(4))) float f32x4;

__device__ __forceinline__ unsigned f2b2(float lo, float hi) {
  // pack two floats to two RNE-rounded bf16 in one u32
  unsigned ul = __builtin_bit_cast(unsigned, lo);
  unsigned uh = __builtin_bit_cast(unsigned, hi);
  ul = (ul + 0x7FFF + ((ul >> 16) & 1)) >> 16;
  uh = (uh + 0x7FFF + ((uh >> 16) & 1));
  return (ul & 0xFFFFu) | (uh & 0xFFFF0000u);
}
__device__ __forceinline__ unsigned short f2b(float f) {
  unsigned u = __builtin_bit_cast(unsigned, f);
  return (unsigned short)((u + 0x7FFF + ((u >> 16) & 1)) >> 16);
}

// ---- kernel 1: tgt bags -> bf16-packed [32][320] (zero k-pad) ----
__global__ __launch_bounds__(256) void prep_kernel(
    const float* __restrict__ char_emb, const float* __restrict__ compo_emb,
    const int* __restrict__ chars, const int* __restrict__ compos,
    unsigned short* __restrict__ tgt_bf) {
  int b = blockIdx.x;
  for (int d = threadIdx.x; d < KP; d += 256) {
    float a = 0.f;
    if (d < DIM) {
      #pragma unroll
      for (int j = 0; j < 4; ++j) {
        int c = chars[b*4 + j];
        if (c != 1) a += char_emb[(size_t)c*DIM + d];
      }
      #pragma unroll
      for (int j = 0; j < 8; ++j) {
        int c = compos[b*8 + j];
        if (c != 1) a += compo_emb[(size_t)c*DIM + d];
      }
    }
    tgt_bf[b*KP + d] = (d < DIM) ? f2b(a) : (unsigned short)0;
  }
}

// ---- kernel 2: MFMA score GEMM: S[b][v] = tgt[b] . word_emb[v] ----
// EXACT R5 structure (the 33 us best). Launched 5x this round to measure
// its true per-dispatch cost from the bench total (idempotent S writes).
__global__ __launch_bounds__(256) void s_gemm_kernel(
    const float4* __restrict__ w4, const unsigned* __restrict__ tgtbf2,
    float* __restrict__ S) {
  __shared__ unsigned short wt[VB][LROW];   // 41984 B
  __shared__ unsigned short tt[BQ][LROW];   // 20992 B
  int tid = threadIdx.x, wv = tid >> 6, lane = tid & 63;
  int vbase = blockIdx.x * VB;

  // stage word tile: 4800 float4, perfectly coalesced (rows contiguous)
  for (int idx = tid; idx < VB*75; idx += 256) {
    float4 x = w4[(size_t)vbase*75 + idx];
    int row = idx / 75, col = idx - row*75;
    unsigned* dst = (unsigned*)&wt[row][col*4];
    dst[0] = f2b2(x.x, x.y);
    dst[1] = f2b2(x.z, x.w);
  }
  if (tid < VB) {            // zero-pad k in [300,320)
    unsigned* dst = (unsigned*)&wt[tid][300];
    #pragma unroll
    for (int j = 0; j < 10; ++j) dst[j] = 0;
  }
  // stage tgt tile: [32][320] bf16 prepacked (incl. zero pad)
  for (int idx = tid; idx < BQ*(KP/2); idx += 256) {
    int row = idx / (KP/2), kk = idx - row*(KP/2);
    ((unsigned*)&tt[row][0])[kk] = tgtbf2[idx];
  }
  __syncthreads();

  // A and B fragments use the same lane->(row,k) formula, so any internal
  // k-permutation cancels in the dot product.
  int ln = lane & 15, g = lane >> 4;
  const unsigned short* brow  = &wt[wv*16 + ln][g*8];
  const unsigned short* arow0 = &tt[ln][g*8];
  const unsigned short* arow1 = &tt[16 + ln][g*8];
  f32x4 acc0 = {0.f,0.f,0.f,0.f}, acc1 = {0.f,0.f,0.f,0.f};
  #pragma unroll
  for (int kb = 0; kb < KP/32; ++kb) {
    short8 bf = *(const short8*)(brow  + kb*32);
    short8 a0 = *(const short8*)(arow0 + kb*32);
    short8 a1 = *(const short8*)(arow1 + kb*32);
    acc0 = __builtin_amdgcn_mfma_f32_16x16x32_bf16(a0, bf, acc0, 0, 0, 0);
    acc1 = __builtin_amdgcn_mfma_f32_16x16x32_bf16(a1, bf, acc1, 0, 0, 0);
  }

  // D: col = lane&15 (v), row = (lane>>4)*4 + reg (b)  [m89-verified]
  int v = vbase + wv*16 + ln;
  #pragma unroll
  for (int r = 0; r < 4; ++r) {
    int b0 = g*4 + r;
    S[(size_t)b0*N_WORD + v]        = acc0[r];
    S[(size_t)(b0 + 16)*N_WORD + v] = acc1[r];
  }
}

// ---- kernel 3: gather S at noise/ctx indices, sum log-sigmoid terms ----
__global__ __launch_bounds__(256) void loss_kernel(
    const float* __restrict__ S, const int* __restrict__ noise,
    const int* __restrict__ ctx, float* __restrict__ partials) {
  float a = 0.f;
  for (int i = blockIdx.x*256 + threadIdx.x; i < NTOT; i += 256*NBLK3) {
    int b = i / PERB;                 // constant divisor -> magic mul
    int idx = noise[i];
    float s = S[(size_t)b*N_WORD + idx];
    a += __logf(1.f/(1.f + __expf(s)) + 1e-32f);
  }
  if (blockIdx.x == 0) {
    int i = threadIdx.x;              // i = b*8 + w covers all 256 (b,w)
    int c = ctx[i];
    float s = (c == 1) ? 0.f : S[(size_t)(i >> 3)*N_WORD + c];
    a += __logf(1.f/(1.f + __expf(-s)));
  }
  #pragma unroll
  for (int off = 32; off > 0; off >>= 1) a += __shfl_down(a, off);
  __shared__ float wsum[4];
  int lane = threadIdx.x & 63, wid = threadIdx.x >> 6;
  if (lane == 0) wsum[wid] = a;
  __syncthreads();
  if (threadIdx.x == 0)
    partials[blockIdx.x] = wsum[0] + wsum[1] + wsum[2] + wsum[3];
}

// ---- kernel 4: deterministic final reduction in double ----
__global__ __launch_bounds__(256) void final_kernel(
    const float* __restrict__ partials, float* __restrict__ out) {
  double a = 0.0;
  for (int i = threadIdx.x; i < NBLK3; i += 256) a += (double)partials[i];
  #pragma unroll
  for (int off = 32; off > 0; off >>= 1) a += __shfl_down(a, off);
  __shared__ double w2[4];
  int lane = threadIdx.x & 63, wid = threadIdx.x >> 6;
  if (lane == 0) w2[wid] = a;
  __syncthreads();
  if (threadIdx.x == 0)
    out[0] = (float)(-(w2[0] + w2[1] + w2[2] + w2[3]) / (double)BQ);
}

extern "C" void kernel_launch(void* const* d_in, const int* in_sizes, int n_in,
                              void* d_out, int out_size, void* d_ws, size_t ws_size,
                              hipStream_t stream) {
  const float* word_emb  = (const float*)d_in[0];   // [32000,300]
  const float* char_emb  = (const float*)d_in[1];   // [8000,300]
  const float* compo_emb = (const float*)d_in[2];   // [1000,300]
  const int*   chars     = (const int*)d_in[3];     // [32,4]
  const int*   compos    = (const int*)d_in[4];     // [32,8]
  const int*   ctx       = (const int*)d_in[5];     // [32,8]
  const int*   noise     = (const int*)d_in[6];     // [32,8,2392]
  float* out = (float*)d_out;

  char* ws = (char*)d_ws;
  unsigned short* tgt_bf   = (unsigned short*)(ws);         // 20480 B [32][320]
  float*          S        = (float*)(ws + 20480);          // 4,096,000 B
  float*          partials = (float*)(ws + 20480 + 4096000);// NBLK3 floats

  prep_kernel<<<BQ, 256, 0, stream>>>(char_emb, compo_emb, chars, compos, tgt_bf);
  // MEASUREMENT: 5 idempotent launches; bench total = base + 4 x g_warm.
  for (int rep = 0; rep < 5; ++rep)
    s_gemm_kernel<<<NGEMB, 256, 0, stream>>>(
        (const float4*)word_emb, (const unsigned*)tgt_bf, S);
  loss_kernel<<<NBLK3, 256, 0, stream>>>(S, noise, ctx, partials);
  final_kernel<<<1, 256, 0, stream>>>(partials, out);
}

// Round 11
// 38.250 us; speedup vs baseline: 1.9628x; 1.9628x over previous
//
#include <hip/hip_runtime.h>

#define N_WORD 32000
#define DIM    300
#define KP     320           // K padded to 10 x 32 for MFMA
#define LROW   328           // LDS row stride in bf16 (656 B: odd*16 -> 2-way max)
#define BQ     32
#define WW     8
#define NNEG   2392
#define PERB   (WW*NNEG)     // 19136
#define NTOT   (BQ*PERB)     // 612352
#define VB     64            // word rows per GEMM block
#define NGEMB  (N_WORD/VB)   // 500
#define NBLK3  1024
#define TOUCHB 2048          // touch blocks (after the 32 prep blocks)
#define W4TOT  2400000       // word_emb float4 count

typedef __attribute__((ext_vector_type(8))) short short8;   // 8 bf16 = 4 VGPR
typedef __attribute__((ext_vector_type(4))) float f32x4;

__device__ __forceinline__ unsigned f2b2(float lo, float hi) {
  // pack two floats to two RNE-rounded bf16 in one u32
  unsigned ul = __builtin_bit_cast(unsigned, lo);
  unsigned uh = __builtin_bit_cast(unsigned, hi);
  ul = (ul + 0x7FFF + ((ul >> 16) & 1)) >> 16;
  uh = (uh + 0x7FFF + ((uh >> 16) & 1));
  return (ul & 0xFFFFu) | (uh & 0xFFFF0000u);
}
__device__ __forceinline__ unsigned short f2b(float f) {
  unsigned u = __builtin_bit_cast(unsigned, f);
  return (unsigned short)((u + 0x7FFF + ((u >> 16) & 1)) >> 16);
}

// ---- kernel 1: blocks 0..31 build tgt bags (bf16-packed [32][320]);
//      blocks 32..2079 pure-stream word_emb to warm L3 for the GEMM. ----
__global__ __launch_bounds__(256) void warm_prep_kernel(
    const float* __restrict__ char_emb, const float* __restrict__ compo_emb,
    const int* __restrict__ chars, const int* __restrict__ compos,
    const float4* __restrict__ w4, unsigned short* __restrict__ tgt_bf) {
  if (blockIdx.x < BQ) {
    int b = blockIdx.x;
    for (int d = threadIdx.x; d < KP; d += 256) {
      float a = 0.f;
      if (d < DIM) {
        #pragma unroll
        for (int j = 0; j < 4; ++j) {
          int c = chars[b*4 + j];
          if (c != 1) a += char_emb[(size_t)c*DIM + d];
        }
        #pragma unroll
        for (int j = 0; j < 8; ++j) {
          int c = compos[b*8 + j];
          if (c != 1) a += compo_emb[(size_t)c*DIM + d];
        }
      }
      tgt_bf[b*KP + d] = (d < DIM) ? f2b(a) : (unsigned short)0;
    }
  } else {
    // fire-and-forget HBM stream: 5 independent float4 loads per thread,
    // all issued back-to-back (no consumer between issues), then asm-sunk.
    const int T = TOUCHB * 256;                       // 524288 threads
    int t = (blockIdx.x - BQ)*256 + threadIdx.x;
    float4 x0 = w4[t];
    float4 x1 = w4[t + T];
    float4 x2 = w4[t + 2*T];
    float4 x3 = w4[t + 3*T];
    float4 x4 = (t + 4*T < W4TOT) ? w4[t + 4*T] : make_float4(0.f,0.f,0.f,0.f);
    float s = x0.x + x1.y + x2.z + x3.w + x4.x;
    asm volatile("" :: "v"(s));                       // keep loads alive
  }
}

// ---- kernel 2: MFMA score GEMM: S[b][v] = tgt[b] . word_emb[v] ----
// R5-exact structure; runs L3-warm behind the touch pass (~10.5 us).
__global__ __launch_bounds__(256) void s_gemm_kernel(
    const float4* __restrict__ w4, const unsigned* __restrict__ tgtbf2,
    float* __restrict__ S) {
  __shared__ unsigned short wt[VB][LROW];   // 41984 B
  __shared__ unsigned short tt[BQ][LROW];   // 20992 B
  int tid = threadIdx.x, wv = tid >> 6, lane = tid & 63;
  int vbase = blockIdx.x * VB;

  // stage word tile: 4800 float4, perfectly coalesced (rows contiguous)
  for (int idx = tid; idx < VB*75; idx += 256) {
    float4 x = w4[(size_t)vbase*75 + idx];
    int row = idx / 75, col = idx - row*75;
    unsigned* dst = (unsigned*)&wt[row][col*4];
    dst[0] = f2b2(x.x, x.y);
    dst[1] = f2b2(x.z, x.w);
  }
  if (tid < VB) {            // zero-pad k in [300,320)
    unsigned* dst = (unsigned*)&wt[tid][300];
    #pragma unroll
    for (int j = 0; j < 10; ++j) dst[j] = 0;
  }
  // stage tgt tile: [32][320] bf16 prepacked (incl. zero pad)
  for (int idx = tid; idx < BQ*(KP/2); idx += 256) {
    int row = idx / (KP/2), kk = idx - row*(KP/2);
    ((unsigned*)&tt[row][0])[kk] = tgtbf2[idx];
  }
  __syncthreads();

  // A and B fragments use the same lane->(row,k) formula, so any internal
  // k-permutation cancels in the dot product.
  int ln = lane & 15, g = lane >> 4;
  const unsigned short* brow  = &wt[wv*16 + ln][g*8];
  const unsigned short* arow0 = &tt[ln][g*8];
  const unsigned short* arow1 = &tt[16 + ln][g*8];
  f32x4 acc0 = {0.f,0.f,0.f,0.f}, acc1 = {0.f,0.f,0.f,0.f};
  #pragma unroll
  for (int kb = 0; kb < KP/32; ++kb) {
    short8 bf = *(const short8*)(brow  + kb*32);
    short8 a0 = *(const short8*)(arow0 + kb*32);
    short8 a1 = *(const short8*)(arow1 + kb*32);
    acc0 = __builtin_amdgcn_mfma_f32_16x16x32_bf16(a0, bf, acc0, 0, 0, 0);
    acc1 = __builtin_amdgcn_mfma_f32_16x16x32_bf16(a1, bf, acc1, 0, 0, 0);
  }

  // D: col = lane&15 (v), row = (lane>>4)*4 + reg (b)  [m89-verified]
  int v = vbase + wv*16 + ln;
  #pragma unroll
  for (int r = 0; r < 4; ++r) {
    int b0 = g*4 + r;
    S[(size_t)b0*N_WORD + v]        = acc0[r];
    S[(size_t)(b0 + 16)*N_WORD + v] = acc1[r];
  }
}

// ---- kernel 3: gather S at noise/ctx indices, sum log-sigmoid terms ----
__global__ __launch_bounds__(256) void loss_kernel(
    const float* __restrict__ S, const int* __restrict__ noise,
    const int* __restrict__ ctx, float* __restrict__ partials) {
  float a = 0.f;
  for (int i = blockIdx.x*256 + threadIdx.x; i < NTOT; i += 256*NBLK3) {
    int b = i / PERB;                 // constant divisor -> magic mul
    int idx = noise[i];
    float s = S[(size_t)b*N_WORD + idx];
    a += __logf(1.f/(1.f + __expf(s)) + 1e-32f);
  }
  if (blockIdx.x == 0) {
    int i = threadIdx.x;              // i = b*8 + w covers all 256 (b,w)
    int c = ctx[i];
    float s = (c == 1) ? 0.f : S[(size_t)(i >> 3)*N_WORD + c];
    a += __logf(1.f/(1.f + __expf(-s)));
  }
  #pragma unroll
  for (int off = 32; off > 0; off >>= 1) a += __shfl_down(a, off);
  __shared__ float wsum[4];
  int lane = threadIdx.x & 63, wid = threadIdx.x >> 6;
  if (lane == 0) wsum[wid] = a;
  __syncthreads();
  if (threadIdx.x == 0)
    partials[blockIdx.x] = wsum[0] + wsum[1] + wsum[2] + wsum[3];
}

// ---- kernel 4: deterministic final reduction in double ----
__global__ __launch_bounds__(256) void final_kernel(
    const float* __restrict__ partials, float* __restrict__ out) {
  double a = 0.0;
  for (int i = threadIdx.x; i < NBLK3; i += 256) a += (double)partials[i];
  #pragma unroll
  for (int off = 32; off > 0; off >>= 1) a += __shfl_down(a, off);
  __shared__ double w2[4];
  int lane = threadIdx.x & 63, wid = threadIdx.x >> 6;
  if (lane == 0) w2[wid] = a;
  __syncthreads();
  if (threadIdx.x == 0)
    out[0] = (float)(-(w2[0] + w2[1] + w2[2] + w2[3]) / (double)BQ);
}

extern "C" void kernel_launch(void* const* d_in, const int* in_sizes, int n_in,
                              void* d_out, int out_size, void* d_ws, size_t ws_size,
                              hipStream_t stream) {
  const float* word_emb  = (const float*)d_in[0];   // [32000,300]
  const float* char_emb  = (const float*)d_in[1];   // [8000,300]
  const float* compo_emb = (const float*)d_in[2];   // [1000,300]
  const int*   chars     = (const int*)d_in[3];     // [32,4]
  const int*   compos    = (const int*)d_in[4];     // [32,8]
  const int*   ctx       = (const int*)d_in[5];     // [32,8]
  const int*   noise     = (const int*)d_in[6];     // [32,8,2392]
  float* out = (float*)d_out;

  char* ws = (char*)d_ws;
  unsigned short* tgt_bf   = (unsigned short*)(ws);         // 20480 B [32][320]
  float*          S        = (float*)(ws + 20480);          // 4,096,000 B
  float*          partials = (float*)(ws + 20480 + 4096000);// NBLK3 floats

  warm_prep_kernel<<<BQ + TOUCHB, 256, 0, stream>>>(
      char_emb, compo_emb, chars, compos, (const float4*)word_emb, tgt_bf);
  s_gemm_kernel<<<NGEMB, 256, 0, stream>>>(
      (const float4*)word_emb, (const unsigned*)tgt_bf, S);
  loss_kernel<<<NBLK3, 256, 0, stream>>>(S, noise, ctx, partials);
  final_kernel<<<1, 256, 0, stream>>>(partials, out);
}

// Round 12
// 36.974 us; speedup vs baseline: 2.0306x; 1.0345x over previous
//
#include <hip/hip_runtime.h>

#define N_WORD 32000
#define DIM    300
#define KP     320           // K padded to 10 x 32 for MFMA
#define LROW   328           // LDS row stride in bf16 (656 B: odd*16 -> 2-way max)
#define BQ     32
#define WW     8
#define NNEG   2392
#define PERB   (WW*NNEG)     // 19136
#define NTOT   (BQ*PERB)     // 612352
#define VB     64            // word rows per GEMM block
#define NGEMB  (N_WORD/VB)   // 500
#define NBLK3  1024

typedef __attribute__((ext_vector_type(8))) short short8;   // 8 bf16 = 4 VGPR
typedef __attribute__((ext_vector_type(4))) float f32x4;

__device__ __forceinline__ unsigned f2b2(float lo, float hi) {
  // pack two floats to two RNE-rounded bf16 in one u32
  unsigned ul = __builtin_bit_cast(unsigned, lo);
  unsigned uh = __builtin_bit_cast(unsigned, hi);
  ul = (ul + 0x7FFF + ((ul >> 16) & 1)) >> 16;
  uh = (uh + 0x7FFF + ((uh >> 16) & 1));
  return (ul & 0xFFFFu) | (uh & 0xFFFF0000u);
}
__device__ __forceinline__ unsigned short f2b(float f) {
  unsigned u = __builtin_bit_cast(unsigned, f);
  return (unsigned short)((u + 0x7FFF + ((u >> 16) & 1)) >> 16);
}

// ---- kernel 1: XCD-aligned warm + prep. Grid = 500 blocks, SAME shape as
// s_gemm, so block j lands on the same XCD as gemm block j (deterministic
// round-robin dispatch). Block j fire-and-forget streams exactly the rows
// [64j, 64j+64) that gemm block j will stage -> they wait in that XCD's L2.
// Blocks 0..31 additionally build the tgt bags (bf16-packed [32][320]). ----
__global__ __launch_bounds__(256) void touch_prep_kernel(
    const float* __restrict__ char_emb, const float* __restrict__ compo_emb,
    const int* __restrict__ chars, const int* __restrict__ compos,
    const float4* __restrict__ w4, unsigned short* __restrict__ tgt_bf) {
  int j = blockIdx.x, tid = threadIdx.x;
  const float4* src = w4 + (size_t)j*(VB*75);    // this gemm-block's tile
  float4 x[19];
  #pragma unroll
  for (int k = 0; k < 18; ++k) x[k] = src[tid + k*256];   // 4608 of 4800
  x[18] = (tid < 192) ? src[4608 + tid] : make_float4(0.f, 0.f, 0.f, 0.f);
  float s = 0.f;
  #pragma unroll
  for (int k = 0; k < 19; ++k) s += x[k].x + x[k].y + x[k].z + x[k].w;
  asm volatile("" :: "v"(s));                    // keep loads alive

  if (j < BQ) {
    int b = j;
    for (int d = tid; d < KP; d += 256) {
      float a = 0.f;
      if (d < DIM) {
        #pragma unroll
        for (int q = 0; q < 4; ++q) {
          int c = chars[b*4 + q];
          if (c != 1) a += char_emb[(size_t)c*DIM + d];
        }
        #pragma unroll
        for (int q = 0; q < 8; ++q) {
          int c = compos[b*8 + q];
          if (c != 1) a += compo_emb[(size_t)c*DIM + d];
        }
      }
      tgt_bf[b*KP + d] = (d < DIM) ? f2b(a) : (unsigned short)0;
    }
  }
}

// ---- kernel 2: MFMA score GEMM (R5-exact): S[b][v] = tgt[b] . word_emb[v] ----
// Runs L2-warm behind the XCD-aligned touch (R10 measured 10.5 us warm).
__global__ __launch_bounds__(256) void s_gemm_kernel(
    const float4* __restrict__ w4, const unsigned* __restrict__ tgtbf2,
    float* __restrict__ S) {
  __shared__ unsigned short wt[VB][LROW];   // 41984 B
  __shared__ unsigned short tt[BQ][LROW];   // 20992 B
  int tid = threadIdx.x, wv = tid >> 6, lane = tid & 63;
  int vbase = blockIdx.x * VB;

  // stage word tile: 4800 float4, perfectly coalesced (rows contiguous)
  for (int idx = tid; idx < VB*75; idx += 256) {
    float4 x = w4[(size_t)vbase*75 + idx];
    int row = idx / 75, col = idx - row*75;
    unsigned* dst = (unsigned*)&wt[row][col*4];
    dst[0] = f2b2(x.x, x.y);
    dst[1] = f2b2(x.z, x.w);
  }
  if (tid < VB) {            // zero-pad k in [300,320)
    unsigned* dst = (unsigned*)&wt[tid][300];
    #pragma unroll
    for (int j = 0; j < 10; ++j) dst[j] = 0;
  }
  // stage tgt tile: [32][320] bf16 prepacked (incl. zero pad)
  for (int idx = tid; idx < BQ*(KP/2); idx += 256) {
    int row = idx / (KP/2), kk = idx - row*(KP/2);
    ((unsigned*)&tt[row][0])[kk] = tgtbf2[idx];
  }
  __syncthreads();

  // A and B fragments use the same lane->(row,k) formula, so any internal
  // k-permutation cancels in the dot product.
  int ln = lane & 15, g = lane >> 4;
  const unsigned short* brow  = &wt[wv*16 + ln][g*8];
  const unsigned short* arow0 = &tt[ln][g*8];
  const unsigned short* arow1 = &tt[16 + ln][g*8];
  f32x4 acc0 = {0.f,0.f,0.f,0.f}, acc1 = {0.f,0.f,0.f,0.f};
  #pragma unroll
  for (int kb = 0; kb < KP/32; ++kb) {
    short8 bf = *(const short8*)(brow  + kb*32);
    short8 a0 = *(const short8*)(arow0 + kb*32);
    short8 a1 = *(const short8*)(arow1 + kb*32);
    acc0 = __builtin_amdgcn_mfma_f32_16x16x32_bf16(a0, bf, acc0, 0, 0, 0);
    acc1 = __builtin_amdgcn_mfma_f32_16x16x32_bf16(a1, bf, acc1, 0, 0, 0);
  }

  // D: col = lane&15 (v), row = (lane>>4)*4 + reg (b)  [m89-verified]
  int v = vbase + wv*16 + ln;
  #pragma unroll
  for (int r = 0; r < 4; ++r) {
    int b0 = g*4 + r;
    S[(size_t)b0*N_WORD + v]        = acc0[r];
    S[(size_t)(b0 + 16)*N_WORD + v] = acc1[r];
  }
}

// ---- kernel 3: gather S at noise/ctx indices, sum log-sigmoid terms ----
__global__ __launch_bounds__(256) void loss_kernel(
    const float* __restrict__ S, const int* __restrict__ noise,
    const int* __restrict__ ctx, float* __restrict__ partials) {
  float a = 0.f;
  for (int i = blockIdx.x*256 + threadIdx.x; i < NTOT; i += 256*NBLK3) {
    int b = i / PERB;                 // constant divisor -> magic mul
    int idx = noise[i];
    float s = S[(size_t)b*N_WORD + idx];
    a += __logf(1.f/(1.f + __expf(s)) + 1e-32f);
  }
  if (blockIdx.x == 0) {
    int i = threadIdx.x;              // i = b*8 + w covers all 256 (b,w)
    int c = ctx[i];
    float s = (c == 1) ? 0.f : S[(size_t)(i >> 3)*N_WORD + c];
    a += __logf(1.f/(1.f + __expf(-s)));
  }
  #pragma unroll
  for (int off = 32; off > 0; off >>= 1) a += __shfl_down(a, off);
  __shared__ float wsum[4];
  int lane = threadIdx.x & 63, wid = threadIdx.x >> 6;
  if (lane == 0) wsum[wid] = a;
  __syncthreads();
  if (threadIdx.x == 0)
    partials[blockIdx.x] = wsum[0] + wsum[1] + wsum[2] + wsum[3];
}

// ---- kernel 4: deterministic final reduction in double ----
__global__ __launch_bounds__(256) void final_kernel(
    const float* __restrict__ partials, float* __restrict__ out) {
  double a = 0.0;
  for (int i = threadIdx.x; i < NBLK3; i += 256) a += (double)partials[i];
  #pragma unroll
  for (int off = 32; off > 0; off >>= 1) a += __shfl_down(a, off);
  __shared__ double w2[4];
  int lane = threadIdx.x & 63, wid = threadIdx.x >> 6;
  if (lane == 0) w2[wid] = a;
  __syncthreads();
  if (threadIdx.x == 0)
    out[0] = (float)(-(w2[0] + w2[1] + w2[2] + w2[3]) / (double)BQ);
}

extern "C" void kernel_launch(void* const* d_in, const int* in_sizes, int n_in,
                              void* d_out, int out_size, void* d_ws, size_t ws_size,
                              hipStream_t stream) {
  const float* word_emb  = (const float*)d_in[0];   // [32000,300]
  const float* char_emb  = (const float*)d_in[1];   // [8000,300]
  const float* compo_emb = (const float*)d_in[2];   // [1000,300]
  const int*   chars     = (const int*)d_in[3];     // [32,4]
  const int*   compos    = (const int*)d_in[4];     // [32,8]
  const int*   ctx       = (const int*)d_in[5];     // [32,8]
  const int*   noise     = (const int*)d_in[6];     // [32,8,2392]
  float* out = (float*)d_out;

  char* ws = (char*)d_ws;
  unsigned short* tgt_bf   = (unsigned short*)(ws);         // 20480 B [32][320]
  float*          S        = (float*)(ws + 20480);          // 4,096,000 B
  float*          partials = (float*)(ws + 20480 + 4096000);// NBLK3 floats

  touch_prep_kernel<<<NGEMB, 256, 0, stream>>>(
      char_emb, compo_emb, chars, compos, (const float4*)word_emb, tgt_bf);
  s_gemm_kernel<<<NGEMB, 256, 0, stream>>>(
      (const float4*)word_emb, (const unsigned*)tgt_bf, S);
  loss_kernel<<<NBLK3, 256, 0, stream>>>(S, noise, ctx, partials);
  final_kernel<<<1, 256, 0, stream>>>(partials, out);
}

// Round 13
// 34.386 us; speedup vs baseline: 2.1834x; 1.0753x over previous
//
#include <hip/hip_runtime.h>

#define N_WORD 32000
#define DIM    300
#define KP     320           // A-side K padded to 10 x 32 (zeros baked by prep)
#define BQ     32
#define WW     8
#define NNEG   2392
#define PERB   (WW*NNEG)     // 19136
#define NTOT   (BQ*PERB)     // 612352
#define VB     32            // word rows per GEMM block
#define NGEMB  (N_WORD/VB)   // 1000
#define NBLK3  1024

typedef __attribute__((ext_vector_type(8))) short short8;   // 8 bf16 = 4 VGPR
typedef __attribute__((ext_vector_type(4))) float f32x4;

__device__ __forceinline__ unsigned f2b2(float lo, float hi) {
  // pack two floats to two RNE-rounded bf16 in one u32
  unsigned ul = __builtin_bit_cast(unsigned, lo);
  unsigned uh = __builtin_bit_cast(unsigned, hi);
  ul = (ul + 0x7FFF + ((ul >> 16) & 1)) >> 16;
  uh = (uh + 0x7FFF + ((uh >> 16) & 1));
  return (ul & 0xFFFFu) | (uh & 0xFFFF0000u);
}
__device__ __forceinline__ unsigned short f2b(float f) {
  unsigned u = __builtin_bit_cast(unsigned, f);
  return (unsigned short)((u + 0x7FFF + ((u >> 16) & 1)) >> 16);
}

__device__ __forceinline__ void gload_lds16(const float* g, float* l) {
  // async global->LDS DMA, 16 B/lane; LDS dest = wave-uniform base + lane*16
  __builtin_amdgcn_global_load_lds(
      (const __attribute__((address_space(1))) void*)g,
      (__attribute__((address_space(3))) void*)l, 16, 0, 0);
}

// ---- kernel 1: tgt bags -> bf16-packed [32][320] (zero k-pad) ----
__global__ __launch_bounds__(256) void prep_kernel(
    const float* __restrict__ char_emb, const float* __restrict__ compo_emb,
    const int* __restrict__ chars, const int* __restrict__ compos,
    unsigned short* __restrict__ tgt_bf) {
  int b = blockIdx.x;
  for (int d = threadIdx.x; d < KP; d += 256) {
    float a = 0.f;
    if (d < DIM) {
      #pragma unroll
      for (int j = 0; j < 4; ++j) {
        int c = chars[b*4 + j];
        if (c != 1) a += char_emb[(size_t)c*DIM + d];
      }
      #pragma unroll
      for (int j = 0; j < 8; ++j) {
        int c = compos[b*8 + j];
        if (c != 1) a += compo_emb[(size_t)c*DIM + d];
      }
    }
    tgt_bf[b*KP + d] = (d < DIM) ? f2b(a) : (unsigned short)0;
  }
}

// ---- kernel 2: MFMA GEMM with async global_load_lds staging (R9 structure,
// now measured CLEAN: R5's partials+double-final chain, no atomic finale).
// 1000 blocks x 4 waves; 38.5 KB LDS -> 4 blocks/CU. Each thread fires 10
// DMAs back-to-back (no VGPR round-trip, no per-load waitcnt) -> ~80 KB/CU
// in flight -> the cold 38.4 MB stream is BW-bound, not latency-bound.
// f32->bf16 conversion happens in the MFMA phase from LDS.
__global__ __launch_bounds__(256) void s_gemm_kernel(
    const float* __restrict__ w, const unsigned short* __restrict__ tgt_bf,
    float* __restrict__ S) {
  __shared__ float wt[VB*DIM + 20];   // 9620 f32 = 38480 B; +20 tail pad
  int tid = threadIdx.x, wv = tid >> 6, lane = tid & 63;
  int vbase = blockIdx.x * VB;
  const float* src = w + (size_t)vbase*DIM;   // 1200-B aligned

  #pragma unroll
  for (int r = 0; r < 9; ++r)        // 9*256 = 2304 of 2400 float4
    gload_lds16(src + (size_t)(r*256 + tid)*4, wt + (r*256 + wv*64)*4);
  if (tid < 96)                       // tail: exec-masked lanes skip
    gload_lds16(src + (size_t)(2304 + tid)*4, wt + (2304 + wv*64)*4);
  if (tid < 20) wt[VB*DIM + tid] = 0.f;   // finite tail pad (NaN x 0 = NaN)
  __syncthreads();                    // drains vmcnt(0): all DMAs landed

  int ln = lane & 15, g = lane >> 4;
  int vt = wv & 1, bt = wv >> 1;
  const float* bp = wt + (vt*16 + ln)*DIM;
  const unsigned short* ap = tgt_bf + (size_t)(bt*16 + ln)*KP;
  f32x4 acc = {0.f, 0.f, 0.f, 0.f};
  #pragma unroll
  for (int kb = 0; kb < KP/32; ++kb) {
    int k0 = kb*32 + g*8;
    // rows 0..30: k>=300 aliases next row (finite, A=0 there); row 31: pad
    float4 b0 = *(const float4*)(bp + k0);
    float4 b1 = *(const float4*)(bp + k0 + 4);
    short8 bf;
    unsigned* bu = (unsigned*)&bf;
    bu[0] = f2b2(b0.x, b0.y); bu[1] = f2b2(b0.z, b0.w);
    bu[2] = f2b2(b1.x, b1.y); bu[3] = f2b2(b1.z, b1.w);
    short8 a = *(const short8*)(ap + kb*32 + g*8);
    acc = __builtin_amdgcn_mfma_f32_16x16x32_bf16(a, bf, acc, 0, 0, 0);
  }

  // D: col = lane&15 (v), row = (lane>>4)*4 + reg (b)  [m89-verified]
  int v = vbase + vt*16 + ln;
  #pragma unroll
  for (int r = 0; r < 4; ++r) {
    int b0 = bt*16 + g*4 + r;
    S[(size_t)b0*N_WORD + v] = acc[r];
  }
}

// ---- kernel 3: gather S at noise/ctx indices, sum log-sigmoid terms ----
__global__ __launch_bounds__(256) void loss_kernel(
    const float* __restrict__ S, const int* __restrict__ noise,
    const int* __restrict__ ctx, float* __restrict__ partials) {
  float a = 0.f;
  for (int i = blockIdx.x*256 + threadIdx.x; i < NTOT; i += 256*NBLK3) {
    int b = i / PERB;                 // constant divisor -> magic mul
    int idx = noise[i];
    float s = S[(size_t)b*N_WORD + idx];
    a += __logf(1.f/(1.f + __expf(s)) + 1e-32f);
  }
  if (blockIdx.x == 0) {
    int i = threadIdx.x;              // i = b*8 + w covers all 256 (b,w)
    int c = ctx[i];
    float s = (c == 1) ? 0.f : S[(size_t)(i >> 3)*N_WORD + c];
    a += __logf(1.f/(1.f + __expf(-s)));
  }
  #pragma unroll
  for (int off = 32; off > 0; off >>= 1) a += __shfl_down(a, off);
  __shared__ float wsum[4];
  int lane = threadIdx.x & 63, wid = threadIdx.x >> 6;
  if (lane == 0) wsum[wid] = a;
  __syncthreads();
  if (threadIdx.x == 0)
    partials[blockIdx.x] = wsum[0] + wsum[1] + wsum[2] + wsum[3];
}

// ---- kernel 4: deterministic final reduction in double ----
__global__ __launch_bounds__(256) void final_kernel(
    const float* __restrict__ partials, float* __restrict__ out) {
  double a = 0.0;
  for (int i = threadIdx.x; i < NBLK3; i += 256) a += (double)partials[i];
  #pragma unroll
  for (int off = 32; off > 0; off >>= 1) a += __shfl_down(a, off);
  __shared__ double w2[4];
  int lane = threadIdx.x & 63, wid = threadIdx.x >> 6;
  if (lane == 0) w2[wid] = a;
  __syncthreads();
  if (threadIdx.x == 0)
    out[0] = (float)(-(w2[0] + w2[1] + w2[2] + w2[3]) / (double)BQ);
}

extern "C" void kernel_launch(void* const* d_in, const int* in_sizes, int n_in,
                              void* d_out, int out_size, void* d_ws, size_t ws_size,
                              hipStream_t stream) {
  const float* word_emb  = (const float*)d_in[0];   // [32000,300]
  const float* char_emb  = (const float*)d_in[1];   // [8000,300]
  const float* compo_emb = (const float*)d_in[2];   // [1000,300]
  const int*   chars     = (const int*)d_in[3];     // [32,4]
  const int*   compos    = (const int*)d_in[4];     // [32,8]
  const int*   ctx       = (const int*)d_in[5];     // [32,8]
  const int*   noise     = (const int*)d_in[6];     // [32,8,2392]
  float* out = (float*)d_out;

  char* ws = (char*)d_ws;
  unsigned short* tgt_bf   = (unsigned short*)(ws);         // 20480 B [32][320]
  float*          S        = (float*)(ws + 20480);          // 4,096,000 B
  float*          partials = (float*)(ws + 20480 + 4096000);// NBLK3 floats

  prep_kernel<<<BQ, 256, 0, stream>>>(char_emb, compo_emb, chars, compos, tgt_bf);
  s_gemm_kernel<<<NGEMB, 256, 0, stream>>>(word_emb, tgt_bf, S);
  loss_kernel<<<NBLK3, 256, 0, stream>>>(S, noise, ctx, partials);
  final_kernel<<<1, 256, 0, stream>>>(partials, out);
}